// Round 10
// baseline (213.108 us; speedup 1.0000x reference)
//
#include <hip/hip_runtime.h>

#define C 128
#define G 8
#define KNN 16
#define QB 4
#define GROUPS 2
#define EPS 1e-5f

typedef unsigned short u16;
typedef __attribute__((ext_vector_type(8))) short short8;   // 8 bf16 = 4 VGPRs
typedef __attribute__((ext_vector_type(4))) float float4v;  // MFMA accumulator

union frag_u { short8 v; u16 u[8]; unsigned d[4]; };

__device__ inline u16 f2bf(float f) {
    unsigned u = __builtin_bit_cast(unsigned, f);
    unsigned r = (u + 0x7fffu + ((u >> 16) & 1u)) >> 16;
    return (u16)r;
}
__device__ inline float bf2f(u16 h) {
    unsigned u = ((unsigned)h) << 16;
    return __builtin_bit_cast(float, u);
}
// hardware packed f32->bf16 (RNE), 1 instr (guide T12 recipe, verified r3-r9)
__device__ inline unsigned pk2(float lo, float hi) {
    unsigned r;
    asm("v_cvt_pk_bf16_f32 %0, %1, %2" : "=v"(r) : "v"(lo), "v"(hi));
    return r;
}
__device__ inline u16 f2bf1(float f) { return (u16)pk2(f, f); }
__device__ inline float bflo(unsigned v) { return __builtin_bit_cast(float, v << 16); }
__device__ inline float bfhi(unsigned v) { return __builtin_bit_cast(float, v & 0xffff0000u); }

// ---------------------------------------------------------------------------
// Prep: swizzle weights into MFMA B-frag bf16 layout.  (verified r4-r9)
// ---------------------------------------------------------------------------
__global__ __launch_bounds__(256) void prep_w(
    const float* __restrict__ Wk, const float* __restrict__ Wv,
    const float* __restrict__ Wq, const float* __restrict__ Wp2,
    const float* __restrict__ Ww1, const float* __restrict__ bp2,
    u16* __restrict__ dst, float* __restrict__ cw1)
{
    __shared__ float w1s[C * G];
    const int b = blockIdx.x, t = threadIdx.x;
    if (b < 16) {
        const int mi = b >> 2, qt = b & 3;
        const float* W = mi == 0 ? Wk : mi == 1 ? Wv : mi == 2 ? Wq : Wp2;
        u16* d = dst + mi * 16384;
        for (int e = qt * 4096 + t; e < (qt + 1) * 4096; e += 256) {
            const int k = e >> 7, n = e & 127;
            const int cb = n >> 4, lan = n & 15;
            const int kk = k >> 5, quad = (k >> 3) & 3, j = k & 7;
            d[(((cb * 4 + kk) * 4 + quad) * 16 + lan) * 8 + j] = f2bf(W[e]);
        }
    } else if (b == 16) {
        u16* d = dst + 4 * 16384;
        for (int e = t; e < 4096; e += 256) {
            const int j = e & 7, lan = (e >> 3) & 15;
            const int quad = (e >> 7) & 3, kk = e >> 9;
            const int k = kk * 32 + quad * 8 + j;
            d[e] = lan < 8 ? f2bf(Ww1[k * G + lan]) : (u16)0;
        }
    } else {
        // Wp2' = Wp2 @ Ww1 -> B-frag; cw1 = bp2 @ Ww1   (Ww1 from LDS)
        u16* d = dst + 4 * 16384 + 4096;
        for (int e = t; e < 4096; e += 256) d[e] = 0;
        for (int e = t; e < C * G; e += 256) w1s[e] = Ww1[e];
        __syncthreads();
#pragma unroll
        for (int it = 0; it < 4; it++) {
            const int k = it * 32 + (t >> 3), g = t & 7;
            const float4* Wr = (const float4*)(Wp2 + k * C);
            float a = 0.f;
#pragma unroll 8
            for (int i4 = 0; i4 < 32; i4++) {
                const float4 wv = Wr[i4];
                a = fmaf(wv.x, w1s[(i4 * 4 + 0) * G + g], a);
                a = fmaf(wv.y, w1s[(i4 * 4 + 1) * G + g], a);
                a = fmaf(wv.z, w1s[(i4 * 4 + 2) * G + g], a);
                a = fmaf(wv.w, w1s[(i4 * 4 + 3) * G + g], a);
            }
            const int kk = k >> 5, quad = (k >> 3) & 3, j = k & 7;
            d[((kk * 4 + quad) * 16 + g) * 8 + j] = f2bf(a);
        }
        if (t < G) {
            float a = 0.f;
#pragma unroll 8
            for (int i = 0; i < C; i++) a = fmaf(bp2[i], w1s[i * G + t], a);
            cw1[t] = a;
        }
    }
}

// ---------------------------------------------------------------------------
// Fused projections.  (verified r4-r9)
// ---------------------------------------------------------------------------
__global__ __launch_bounds__(256) void proj_all(
    const float* __restrict__ Xc, const float* __restrict__ Xq,
    const u16* __restrict__ PWk, const float* __restrict__ bk,
    const float* __restrict__ gk, const float* __restrict__ betak,
    const u16* __restrict__ PWv, const float* __restrict__ bv,
    const u16* __restrict__ PWq, const float* __restrict__ bq,
    const float* __restrict__ gq, const float* __restrict__ betaq,
    const u16* __restrict__ PWw1b,
    u16* __restrict__ vout, u16* __restrict__ Kp, u16* __restrict__ Qp,
    int nkv)
{
    __shared__ u16 Xs[64 * 136];
    const int t = threadIdx.x;
    const int w = t >> 6, l = t & 63;
    const int quad = l >> 4, lan = l & 15;
    const bool isq = (int)blockIdx.x >= nkv;
    const long long row0 = (long long)(isq ? blockIdx.x - nkv : blockIdx.x) * 64;
    const float* X = isq ? Xq : Xc;

    // stage X tile -> bf16 LDS (hw cvt_pk)
    {
        const float4* Xv = (const float4*)(X + row0 * C);
#pragma unroll
        for (int i = 0; i < 8; i++) {
            const int e = t + 256 * i;
            const int r = e >> 5, c4 = e & 31;
            const float4 f = Xv[e];
            uint2 p;
            p.x = pk2(f.x, f.y);
            p.y = pk2(f.z, f.w);
            *(uint2*)(&Xs[r * 136 + c4 * 4]) = p;
        }
    }
    __syncthreads();

    if (!isq) {
        // ---- v pass (bias in acc init), packed bf16 in regs ----
        unsigned vp[2][4][2];
        {
            short8 Bf[2][4];
#pragma unroll
            for (int ct = 0; ct < 2; ct++) {
                const int cb = w * 2 + ct;
#pragma unroll
                for (int kk = 0; kk < 4; kk++)
                    Bf[ct][kk] = *(const short8*)(PWv + (((cb * 4 + kk) * 4 + quad) * 16 + lan) * 8);
            }
            const float b0v = bv[w * 32 + lan], b1v = bv[w * 32 + 16 + lan];
            float4v acc[2][4];
#pragma unroll
            for (int rt = 0; rt < 4; rt++) {
                acc[0][rt] = (float4v)b0v;
                acc[1][rt] = (float4v)b1v;
            }
#pragma unroll
            for (int rt = 0; rt < 4; rt++)
#pragma unroll
                for (int kk = 0; kk < 4; kk++) {
                    const short8 A = *(const short8*)(&Xs[(rt * 16 + lan) * 136 + kk * 32 + quad * 8]);
#pragma unroll
                    for (int ct = 0; ct < 2; ct++)
                        acc[ct][rt] = __builtin_amdgcn_mfma_f32_16x16x32_bf16(
                            A, Bf[ct][kk], acc[ct][rt], 0, 0, 0);
                }
#pragma unroll
            for (int ct = 0; ct < 2; ct++)
#pragma unroll
                for (int rt = 0; rt < 4; rt++)
#pragma unroll
                    for (int h = 0; h < 2; h++)
                        vp[ct][rt][h] = pk2(acc[ct][rt][2 * h], acc[ct][rt][2 * h + 1]);
        }
        // ---- k pass (bias in acc init), kept in regs ----
        float4v acck[2][4];
        {
            short8 Bf[2][4];
#pragma unroll
            for (int ct = 0; ct < 2; ct++) {
                const int cb = w * 2 + ct;
#pragma unroll
                for (int kk = 0; kk < 4; kk++)
                    Bf[ct][kk] = *(const short8*)(PWk + (((cb * 4 + kk) * 4 + quad) * 16 + lan) * 8);
            }
            const float b0k = bk[w * 32 + lan], b1k = bk[w * 32 + 16 + lan];
#pragma unroll
            for (int rt = 0; rt < 4; rt++) {
                acck[0][rt] = (float4v)b0k;
                acck[1][rt] = (float4v)b1k;
            }
#pragma unroll
            for (int rt = 0; rt < 4; rt++)
#pragma unroll
                for (int kk = 0; kk < 4; kk++) {
                    const short8 A = *(const short8*)(&Xs[(rt * 16 + lan) * 136 + kk * 32 + quad * 8]);
#pragma unroll
                    for (int ct = 0; ct < 2; ct++)
                        acck[ct][rt] = __builtin_amdgcn_mfma_f32_16x16x32_bf16(
                            A, Bf[ct][kk], acck[ct][rt], 0, 0, 0);
                }
        }
        __syncthreads();   // Xs A-reads done

        // k epilogue: y = fma(acc, sc, sh); relu -> Xs (row-major bf16)
#pragma unroll
        for (int ct = 0; ct < 2; ct++) {
            const int cg = w * 32 + ct * 16 + lan;
            const float sc = gk[cg] * rsqrtf(1.f + EPS);
            const float sh = betak[cg];
#pragma unroll
            for (int rt = 0; rt < 4; rt++)
#pragma unroll
                for (int reg = 0; reg < 4; reg++) {
                    float y = fmaf(acck[ct][rt][reg], sc, sh);
                    y = y > 0.f ? y : 0.f;
                    Xs[(rt * 16 + quad * 4 + reg) * 136 + cg] = f2bf1(y);
                }
        }
        __syncthreads();

        // K' = k @ Ww1 : wave w handles rows [16w,16w+16)
        {
            short8 Bw[4];
#pragma unroll
            for (int kk = 0; kk < 4; kk++)
                Bw[kk] = *(const short8*)(PWw1b + ((kk * 4 + quad) * 16 + lan) * 8);
            float4v ka = (float4v)0.f;
#pragma unroll
            for (int kk = 0; kk < 4; kk++) {
                const short8 A = *(const short8*)(&Xs[(w * 16 + lan) * 136 + kk * 32 + quad * 8]);
                ka = __builtin_amdgcn_mfma_f32_16x16x32_bf16(A, Bw[kk], ka, 0, 0, 0);
            }
            if (lan < G) {
#pragma unroll
                for (int reg = 0; reg < 4; reg++)
                    Kp[(row0 + w * 16 + quad * 4 + reg) * G + lan] = f2bf1(ka[reg]);
            }
        }
        __syncthreads();   // Xs K'-reads done

        // v epilogue (unpack) -> Xs -> coalesced store
#pragma unroll
        for (int ct = 0; ct < 2; ct++) {
            const int cg = w * 32 + ct * 16 + lan;
#pragma unroll
            for (int rt = 0; rt < 4; rt++)
#pragma unroll
                for (int h = 0; h < 2; h++) {
                    Xs[(rt * 16 + quad * 4 + 2 * h) * 136 + cg]     = (u16)(vp[ct][rt][h] & 0xffffu);
                    Xs[(rt * 16 + quad * 4 + 2 * h + 1) * 136 + cg] = (u16)(vp[ct][rt][h] >> 16);
                }
        }
        __syncthreads();
#pragma unroll
        for (int i = 0; i < 4; i++) {
            const int e = t + 256 * i;
            const int r = e >> 4, cc = (e & 15) * 8;
            *(short8*)(vout + (row0 + r) * C + cc) = *(const short8*)(&Xs[r * 136 + cc]);
        }
    } else {
        // ---- q path: bias in acc init; folded bn+relu; Q' = q@Ww1 ----
        float4v acc[2][4];
        {
            short8 Bf[2][4];
#pragma unroll
            for (int ct = 0; ct < 2; ct++) {
                const int cb = w * 2 + ct;
#pragma unroll
                for (int kk = 0; kk < 4; kk++)
                    Bf[ct][kk] = *(const short8*)(PWq + (((cb * 4 + kk) * 4 + quad) * 16 + lan) * 8);
            }
            const float b0q = bq[w * 32 + lan], b1q = bq[w * 32 + 16 + lan];
#pragma unroll
            for (int rt = 0; rt < 4; rt++) {
                acc[0][rt] = (float4v)b0q;
                acc[1][rt] = (float4v)b1q;
            }
#pragma unroll
            for (int rt = 0; rt < 4; rt++)
#pragma unroll
                for (int kk = 0; kk < 4; kk++) {
                    const short8 A = *(const short8*)(&Xs[(rt * 16 + lan) * 136 + kk * 32 + quad * 8]);
#pragma unroll
                    for (int ct = 0; ct < 2; ct++)
                        acc[ct][rt] = __builtin_amdgcn_mfma_f32_16x16x32_bf16(
                            A, Bf[ct][kk], acc[ct][rt], 0, 0, 0);
                }
        }
        __syncthreads();
#pragma unroll
        for (int ct = 0; ct < 2; ct++) {
            const int cg = w * 32 + ct * 16 + lan;
            const float sc = gq[cg] * rsqrtf(1.f + EPS);
            const float sh = betaq[cg];
#pragma unroll
            for (int rt = 0; rt < 4; rt++)
#pragma unroll
                for (int reg = 0; reg < 4; reg++) {
                    float y = fmaf(acc[ct][rt][reg], sc, sh);
                    y = y > 0.f ? y : 0.f;
                    Xs[(rt * 16 + quad * 4 + reg) * 136 + cg] = f2bf1(y);
                }
        }
        __syncthreads();
        {
            short8 Bw[4];
#pragma unroll
            for (int kk = 0; kk < 4; kk++)
                Bw[kk] = *(const short8*)(PWw1b + ((kk * 4 + quad) * 16 + lan) * 8);
            float4v qa = (float4v)0.f;
#pragma unroll
            for (int kk = 0; kk < 4; kk++) {
                const short8 A = *(const short8*)(&Xs[(w * 16 + lan) * 136 + kk * 32 + quad * 8]);
                qa = __builtin_amdgcn_mfma_f32_16x16x32_bf16(A, Bw[kk], qa, 0, 0, 0);
            }
            if (lan < G) {
#pragma unroll
                for (int reg = 0; reg < 4; reg++)
                    Qp[(row0 + w * 16 + quad * 4 + reg) * G + lan] = f2bf1(qa[reg]);
            }
        }
    }
}

// ---------------------------------------------------------------------------
// Attention v6.12 = verified r9 attn + GROUPS=2 time-multiplex:
//   - grid halved (2048 blocks); block processes 2 query-groups sequentially
//   - small buffers (kgs/ps4/idxs/qps) double-buffered [2]; BOTH groups
//     staged up-front in P0 (no late LDS writes, no prefetch dance)
//   - vg regs reloaded for group 1 right after group 0's P3 consumes them
//   - per-group phase code byte-identical to r9; +1 barrier at group boundary
// ---------------------------------------------------------------------------
__global__ __launch_bounds__(256) void attn6(
    const u16* __restrict__ vbuf, const u16* __restrict__ Kp,
    const u16* __restrict__ Qp,
    const float* __restrict__ qcoord, const float* __restrict__ ccoord,
    const float* __restrict__ Wp1, const float* __restrict__ bp1,
    const float* __restrict__ gp1, const float* __restrict__ betap1,
    const u16* __restrict__ PWp2, const float* __restrict__ bp2,
    const u16* __restrict__ PWp2pb, const float* __restrict__ cw1,
    const float* __restrict__ bw1,
    const float* __restrict__ gw1, const float* __restrict__ betaw1,
    const float* __restrict__ Ww2, const float* __restrict__ bw2,
    const int* __restrict__ knn, float* __restrict__ out)
{
    __shared__ u16    fA[64 * 136];          // h1 -> peb -> val (per group)
    __shared__ u16    kgs[GROUPS][64 * G];   // gathered K' rows (bf16)
    __shared__ float  qps[GROUPS][QB * G];   // Q' rows (fp32)
    __shared__ float  pebp[64 * G];          // PEB' (fp32, per group)
    __shared__ float  cw1s[G];
    __shared__ float  ww2s[G * G];           // Ww2 staged once
    __shared__ float4 ps4[GROUPS][64];       // packed pos (x,y,z,0)
    __shared__ int    idxs[GROUPS][64];
    __shared__ float  wl[QB * 16 * G];       // hw -> weights (in place)

    const int t = threadIdx.x;
    const int w = t >> 6, l = t & 63;
    const int quad = l >> 4, lan = l & 15;
    const int mbase = blockIdx.x * (QB * GROUPS);
    const int rsub = t >> 4;              // 0..15
    const int c8 = (t & 15) * 8;

    // ---- P0: knn for both groups; stage BOTH groups' small buffers;
    //          v gather (regs) for group 0 only ----
    int knnreg[GROUPS][4];
#pragma unroll
    for (int gg = 0; gg < GROUPS; gg++)
#pragma unroll
        for (int p = 0; p < 4; p++)
            knnreg[gg][p] = knn[(mbase + gg * QB) * KNN + p * 16 + rsub];

    float mfr[4];
    frag_u vg[4];
#pragma unroll
    for (int p = 0; p < 4; p++) {
        const int ii = knnreg[0][p];
        mfr[p] = ii >= 0 ? 1.f : 0.f;
        const size_t i0 = ii >= 0 ? ii : 0;
        vg[p].v = *(const short8*)(vbuf + i0 * C + c8);
    }
    if (t < 64) {
#pragma unroll
        for (int gg = 0; gg < GROUPS; gg++) {
            const int q = t >> 4;
            const int ii = knn[(mbase + gg * QB) * KNN + t];
            const float mf = ii >= 0 ? 1.f : 0.f;
            const int i0 = ii >= 0 ? ii : 0;
            idxs[gg][t] = ii;
            float4 p4;
            p4.x = (ccoord[i0 * 3 + 0] - qcoord[(mbase + gg * QB + q) * 3 + 0]) * mf;
            p4.y = (ccoord[i0 * 3 + 1] - qcoord[(mbase + gg * QB + q) * 3 + 1]) * mf;
            p4.z = (ccoord[i0 * 3 + 2] - qcoord[(mbase + gg * QB + q) * 3 + 2]) * mf;
            p4.w = 0.f;
            ps4[gg][t] = p4;
            *(short8*)(&kgs[gg][t * G]) = *(const short8*)(Kp + (size_t)i0 * G);
        }
    } else if (t < 64 + QB) {
        const int p = t - 64;
#pragma unroll
        for (int gg = 0; gg < GROUPS; gg++) {
            frag_u qv;
            qv.v = *(const short8*)(Qp + (size_t)(mbase + gg * QB + p) * G);
#pragma unroll
            for (int j = 0; j < G; j++) qps[gg][p * G + j] = bf2f(qv.u[j]);
        }
    } else if (t < 68 + G) {
        cw1s[t - 68] = cw1[t - 68];
    } else if (t < 76 + G * G) {
        ww2s[t - 76] = Ww2[t - 76];
    }
    __syncthreads();

#pragma unroll
    for (int gi = 0; gi < GROUPS; gi++) {
        const int m0 = mbase + gi * QB;

        // ---- P1: h1 = relu(bn(pos @ Wp1 + bp1)) -> fA (4r x 8c / thread) ----
        {
            const float rsq = rsqrtf(1.f + EPS);
            const float4 gA = *(const float4*)(&gp1[c8]);
            const float4 gB = *(const float4*)(&gp1[c8 + 4]);
            const float4 bA = *(const float4*)(&bp1[c8]);
            const float4 bB = *(const float4*)(&bp1[c8 + 4]);
            const float4 eA = *(const float4*)(&betap1[c8]);
            const float4 eB = *(const float4*)(&betap1[c8 + 4]);
            const float4 xA = *(const float4*)(&Wp1[c8]);
            const float4 xB = *(const float4*)(&Wp1[c8 + 4]);
            const float4 yA = *(const float4*)(&Wp1[C + c8]);
            const float4 yB = *(const float4*)(&Wp1[C + c8 + 4]);
            const float4 zA = *(const float4*)(&Wp1[2 * C + c8]);
            const float4 zB = *(const float4*)(&Wp1[2 * C + c8 + 4]);
            const float gs[8] = {gA.x, gA.y, gA.z, gA.w, gB.x, gB.y, gB.z, gB.w};
            const float bs[8] = {bA.x, bA.y, bA.z, bA.w, bB.x, bB.y, bB.z, bB.w};
            const float es[8] = {eA.x, eA.y, eA.z, eA.w, eB.x, eB.y, eB.z, eB.w};
            const float xs[8] = {xA.x, xA.y, xA.z, xA.w, xB.x, xB.y, xB.z, xB.w};
            const float ys[8] = {yA.x, yA.y, yA.z, yA.w, yB.x, yB.y, yB.z, yB.w};
            const float zs[8] = {zA.x, zA.y, zA.z, zA.w, zB.x, zB.y, zB.z, zB.w};
            float w0f[8], w1f[8], w2f[8], bbf[8];
#pragma unroll
            for (int i2 = 0; i2 < 8; i2++) {
                const float sc = gs[i2] * rsq;
                w0f[i2] = xs[i2] * sc;
                w1f[i2] = ys[i2] * sc;
                w2f[i2] = zs[i2] * sc;
                bbf[i2] = fmaf(bs[i2], sc, es[i2]);
            }
#pragma unroll
            for (int rr = 0; rr < 4; rr++) {
                const int r = rsub * 4 + rr;
                const float4 p4 = ps4[gi][r];
                frag_u o;
#pragma unroll
                for (int dd = 0; dd < 4; dd++) {
                    const int ca = 2 * dd, cb2 = 2 * dd + 1;
                    float ya = fmaf(p4.x, w0f[ca],
                               fmaf(p4.y, w1f[ca], fmaf(p4.z, w2f[ca], bbf[ca])));
                    float yb = fmaf(p4.x, w0f[cb2],
                               fmaf(p4.y, w1f[cb2], fmaf(p4.z, w2f[cb2], bbf[cb2])));
                    ya = ya > 0.f ? ya : 0.f;
                    yb = yb > 0.f ? yb : 0.f;
                    o.d[dd] = pk2(ya, yb);
                }
                *(short8*)(&fA[r * 136 + c8]) = o.v;
            }
        }
        __syncthreads();

        // ---- P2: peb = h1 @ Wp2 (+bp2 via acc init) + PEB' = h1 @ Wp2' ----
        float4v acc[2][4];
        float4v pp = (float4v)0.f;
        {
            short8 Bf[2][4];
#pragma unroll
            for (int ct = 0; ct < 2; ct++) {
                const int cb = w * 2 + ct;
#pragma unroll
                for (int kk = 0; kk < 4; kk++)
                    Bf[ct][kk] = *(const short8*)(PWp2 + (((cb * 4 + kk) * 4 + quad) * 16 + lan) * 8);
            }
            const float b0 = bp2[w * 32 + lan], b1 = bp2[w * 32 + 16 + lan];
#pragma unroll
            for (int q = 0; q < 4; q++) {
                acc[0][q] = (float4v)b0;
                acc[1][q] = (float4v)b1;
            }
#pragma unroll
            for (int q = 0; q < 4; q++)
#pragma unroll
                for (int kk = 0; kk < 4; kk++) {
                    const short8 A = *(const short8*)(&fA[(q * 16 + lan) * 136 + kk * 32 + quad * 8]);
#pragma unroll
                    for (int ct = 0; ct < 2; ct++)
                        acc[ct][q] = __builtin_amdgcn_mfma_f32_16x16x32_bf16(
                            A, Bf[ct][kk], acc[ct][q], 0, 0, 0);
                }
            // PEB': wave w -> rows [16w,16w+16)
#pragma unroll
            for (int kk = 0; kk < 4; kk++) {
                const short8 Bp = *(const short8*)(PWp2pb + ((kk * 4 + quad) * 16 + lan) * 8);
                const short8 A = *(const short8*)(&fA[(w * 16 + lan) * 136 + kk * 32 + quad * 8]);
                pp = __builtin_amdgcn_mfma_f32_16x16x32_bf16(A, Bp, pp, 0, 0, 0);
            }
        }
        __syncthreads();   // all h1 reads done

        // ---- P2b: scatter peb (bf16, in place) and PEB' (fp32) ----
        {
#pragma unroll
            for (int ct = 0; ct < 2; ct++)
#pragma unroll
                for (int q = 0; q < 4; q++)
#pragma unroll
                    for (int reg = 0; reg < 4; reg++)
                        fA[(q * 16 + quad * 4 + reg) * 136 + w * 32 + ct * 16 + lan] =
                            f2bf1(acc[ct][q][reg]);
            if (lan < G) {
#pragma unroll
                for (int reg = 0; reg < 4; reg++)
                    pebp[(w * 16 + quad * 4 + reg) * G + lan] = pp[reg];
            }
        }
        __syncthreads();

        // ---- P3: val = vg*mf + peb -> fA (in place) ----
        {
#pragma unroll
            for (int p = 0; p < 4; p++) {
                const int r = p * 16 + rsub;
                const float mf = mfr[p];
                frag_u peb, o;
                peb.v = *(const short8*)(&fA[r * 136 + c8]);
#pragma unroll
                for (int dd = 0; dd < 4; dd++) {
                    const unsigned pv = peb.d[dd], vv = vg[p].d[dd];
                    o.d[dd] = pk2(fmaf(bflo(vv), mf, bflo(pv)),
                                  fmaf(bfhi(vv), mf, bfhi(pv)));
                }
                *(short8*)(&fA[r * 136 + c8]) = o.v;   // exclusive slot
            }
        }
        // vg consumed: issue group-1 v gather now (covered by P3b..P5 latency)
        if (gi + 1 < GROUPS) {
#pragma unroll
            for (int p = 0; p < 4; p++) {
                const int ii = knnreg[gi + 1][p];
                mfr[p] = ii >= 0 ? 1.f : 0.f;
                const size_t i0 = ii >= 0 ? ii : 0;
                vg[p].v = *(const short8*)(vbuf + i0 * C + c8);
            }
        }
        // ---- P3b: logits -> wl (ALL lanes) ----
        {
            const int j = l & 15;
            const int r = (w << 4) + j;
            const float mf = idxs[gi][r] >= 0 ? 1.f : 0.f;
            const int g0 = 2 * quad, g1 = g0 + 1;
            const float L0 = bf2f(kgs[gi][r * G + g0]) * mf - qps[gi][w * G + g0]
                           + pebp[r * G + g0] + cw1s[g0] + bw1[g0];
            const float L1 = bf2f(kgs[gi][r * G + g1]) * mf - qps[gi][w * G + g1]
                           + pebp[r * G + g1] + cw1s[g1] + bw1[g1];
            const float y0 = L0 * (gw1[g0] * rsqrtf(1.f + EPS)) + betaw1[g0];
            const float y1 = L1 * (gw1[g1] * rsqrtf(1.f + EPS)) + betaw1[g1];
            wl[w * 128 + j * 8 + g0] = y0 > 0.f ? y0 : 0.f;
            wl[w * 128 + j * 8 + g1] = y1 > 0.f ? y1 : 0.f;
        }
        __syncthreads();

        // ---- P5: a = hw@Ww2 + bw2; softmax over j (16-lane bfly); *mask ----
        {
            const int j = l & 15;
            const int g0 = 2 * quad, g1 = g0 + 1;
            float hw_[8];
#pragma unroll
            for (int g = 0; g < 8; g++) hw_[g] = wl[w * 128 + j * 8 + g];
            float a0 = bw2[g0], a1 = bw2[g1];
#pragma unroll
            for (int g = 0; g < 8; g++) {
                a0 = fmaf(hw_[g], ww2s[g * 8 + g0], a0);
                a1 = fmaf(hw_[g], ww2s[g * 8 + g1], a1);
            }
            float mx0 = a0, mx1 = a1;
#pragma unroll
            for (int off = 1; off < 16; off <<= 1) {
                mx0 = fmaxf(mx0, __shfl_xor(mx0, off));
                mx1 = fmaxf(mx1, __shfl_xor(mx1, off));
            }
            const float e0 = __expf(a0 - mx0), e1 = __expf(a1 - mx1);
            float s0 = e0, s1 = e1;
#pragma unroll
            for (int off = 1; off < 16; off <<= 1) {
                s0 += __shfl_xor(s0, off);
                s1 += __shfl_xor(s1, off);
            }
            const float mf = idxs[gi][(w << 4) + j] >= 0 ? 1.f : 0.f;
            wl[w * 128 + j * 8 + g0] = e0 * (1.f / s0) * mf;
            wl[w * 128 + j * 8 + g1] = e1 * (1.f / s1) * mf;
        }
        __syncthreads();

        // ---- P6: out[q][c] = sum_j val[j][c] * w[j][c>>4]  (paired cols) ----
        {
            const int q = t >> 6;            // wave = query
            const int pc = t & 63;
            const int c0 = 2 * pc;
            const int g = pc >> 3;           // (2*pc)>>4
            float s0 = 0.f, s1 = 0.f;
#pragma unroll
            for (int j = 0; j < KNN; j++) {
                const unsigned v = *(const unsigned*)(&fA[(q * 16 + j) * 136 + c0]);
                const float wv = wl[q * 128 + j * 8 + g];
                s0 = fmaf(bflo(v), wv, s0);
                s1 = fmaf(bfhi(v), wv, s1);
            }
            *(float2*)(&out[(size_t)(m0 + q) * C + c0]) = make_float2(s0, s1);
        }

        // group boundary: fA and wl are rewritten by next group's P1/P3b
        if (gi + 1 < GROUPS) __syncthreads();
    }
}

// ---------------------------------------------------------------------------
extern "C" void kernel_launch(void* const* d_in, const int* in_sizes, int n_in,
                              void* d_out, int out_size, void* d_ws, size_t ws_size,
                              hipStream_t stream)
{
    const float* query_feat    = (const float*)d_in[0];
    const float* context_feat  = (const float*)d_in[1];
    const float* query_coord   = (const float*)d_in[2];
    const float* context_coord = (const float*)d_in[3];
    const float* Wq    = (const float*)d_in[4];
    const float* bq    = (const float*)d_in[5];
    const float* gq    = (const float*)d_in[6];
    const float* betaq = (const float*)d_in[7];
    const float* Wk    = (const float*)d_in[8];
    const float* bk    = (const float*)d_in[9];
    const float* gk    = (const float*)d_in[10];
    const float* betak = (const float*)d_in[11];
    const float* Wv    = (const float*)d_in[12];
    const float* bv    = (const float*)d_in[13];
    const float* Wp1   = (const float*)d_in[14];
    const float* bp1   = (const float*)d_in[15];
    const float* gp1   = (const float*)d_in[16];
    const float* betap1= (const float*)d_in[17];
    const float* Wp2   = (const float*)d_in[18];
    const float* bp2   = (const float*)d_in[19];
    const float* Ww1   = (const float*)d_in[20];
    const float* bw1   = (const float*)d_in[21];
    const float* gw1   = (const float*)d_in[22];
    const float* betaw1= (const float*)d_in[23];
    const float* Ww2   = (const float*)d_in[24];
    const float* bw2   = (const float*)d_in[25];
    const int*   knn   = (const int*)d_in[26];

    const int M = in_sizes[0] / C;   // 16384
    const int N = in_sizes[1] / C;   // 131072

    // workspace: v (N*C bf16) | K' (N*G bf16) | Q' (M*G bf16) | prepped weights | cw1
    u16* vb = (u16*)d_ws;
    u16* Kp = vb + (size_t)N * C;
    u16* Qp = Kp + (size_t)N * G;
    u16* pw = Qp + (size_t)M * G;
    u16* pWk    = pw;
    u16* pWv    = pw + 16384;
    u16* pWq    = pw + 2 * 16384;
    u16* pWp2   = pw + 3 * 16384;
    u16* pWw1b  = pw + 4 * 16384;
    u16* pWp2pb = pw + 4 * 16384 + 4096;
    float* cw1  = (float*)(pw + 4 * 16384 + 2 * 4096);

    prep_w<<<18, 256, 0, stream>>>(Wk, Wv, Wq, Wp2, Ww1, bp2, pw, cw1);
    proj_all<<<N / 64 + M / 64, 256, 0, stream>>>(
        context_feat, query_feat,
        pWk, bk, gk, betak, pWv, bv,
        pWq, bq, gq, betaq, pWw1b,
        vb, Kp, Qp, N / 64);
    attn6<<<M / (QB * GROUPS), 256, 0, stream>>>(
        vb, Kp, Qp, query_coord, context_coord,
        Wp1, bp1, gp1, betap1, pWp2, bp2,
        pWp2pb, cw1, bw1, gw1, betaw1, Ww2, bw2,
        knn, (float*)d_out);
}